// Round 5
// baseline (91.132 us; speedup 1.0000x reference)
//
#include <hip/hip_runtime.h>

// LogSparseAttention: B=2, L=S=2048, H=8, E=D=64, fp32 in/out.
// Mask (win_len=sub_len=2048, log_l=11):
//   l < 22  : causal prefix 0..l
//   l >= 22 : {l-10..l} U {l-10-2^j >= 0, j=0..10}  (<= 22 columns)
//
// R3: 4 rows/wave (4 heads of same (b,l)), 16 lanes/row, pure-DPP reduce.
// R4: XCD-aware block swizzle (contiguous l-slab per XCD).
// R5: bf16-packed K+V staging in d_ws. Wall was L2 footprint: one resident
//     wave generation -> whole 512-l slab live per XCD, 6.3 MB > 4 MB L2,
//     tail columns thrash L3 (~16 TB/s effective). bf16 halves bytes:
//     slab 3.1 MB fits L2, logical traffic 377->188 MB, and interleaved
//     K|V packing merges both reads into ONE dwordx4 per column.

constexpr int B = 2, L = 2048, S = 2048, H = 8, E = 64;
constexpr int LOGL = 11;
constexpr int MAXC = 2 * LOGL;           // 22
constexpr int ROWS = B * L * H;          // 32768
constexpr int WPB  = 4;                  // waves per block
constexpr int WAVES = ROWS / 4;          // 8192 (4 rows per wave)
constexpr int NBLK  = WAVES / WPB;       // 2048
constexpr size_t PACK_BYTES = (size_t)B * S * H * 16 * 16;   // 8 MiB

template<int CTRL>
__device__ __forceinline__ float dpp_add(float x) {
    int y = __builtin_amdgcn_update_dpp(0, __float_as_int(x), CTRL, 0xF, 0xF, true);
    return x + __int_as_float(y);
}

// pack two fp32 -> bf16x2 (RNE), a in low 16, b in high 16
__device__ __forceinline__ unsigned pbf(float a, float b) {
    unsigned ua = __float_as_uint(a), ub = __float_as_uint(b);
    ua += 0x7fffu + ((ua >> 16) & 1u);
    ub += 0x7fffu + ((ub >> 16) & 1u);
    return (ua >> 16) | (ub & 0xffff0000u);
}
__device__ __forceinline__ float bflo(unsigned u) { return __uint_as_float(u << 16); }
__device__ __forceinline__ float bfhi(unsigned u) { return __uint_as_float(u & 0xffff0000u); }

// ---------------- prepass: fp32 K,V -> packed bf16 {K4|V4} ----------------
__global__ __launch_bounds__(256)
void pack_kv(const float4* __restrict__ K4, const float4* __restrict__ V4,
             uint4* __restrict__ P) {
    const int t = blockIdx.x * 256 + threadIdx.x;    // (b,s,h,g) flat, g=e/4
    const float4 k = K4[t];
    const float4 v = V4[t];
    P[t] = make_uint4(pbf(k.x, k.y), pbf(k.z, k.w),
                      pbf(v.x, v.y), pbf(v.z, v.w));
}

// ---------------- shared column-list builder ----------------
__device__ __forceinline__ void build_cols(int l, int* cols, bool* val) {
    if (l < 2 * LOGL) {
#pragma unroll
        for (int i = 0; i < MAXC; ++i) {
            val[i]  = (i <= l);
            cols[i] = val[i] ? i : 0;
        }
    } else {
#pragma unroll
        for (int j = 0; j < LOGL; ++j) {
            cols[j] = l - (LOGL - 1) + j;
            val[j]  = true;
        }
#pragma unroll
        for (int j = 0; j < LOGL; ++j) {
            int c = l - (LOGL - 1) - (1 << j);
            val[LOGL + j]  = (c >= 0);
            cols[LOGL + j] = (c >= 0) ? c : 0;
        }
    }
#pragma unroll
    for (int i = 0; i < MAXC; ++i)
        cols[i] = __builtin_amdgcn_readfirstlane(cols[i]);   // wave-uniform -> SGPR
}

// ---------------- main kernel (bf16-packed K/V path) ----------------
__global__ __launch_bounds__(WPB * 64)
void logsparse_attn_bf(const float4* __restrict__ Q4,
                       const uint4* __restrict__ P,
                       float4* __restrict__ O4) {
    const int logical = (blockIdx.x & 7) * (NBLK / 8) + (blockIdx.x >> 3);
    const int lane = threadIdx.x & 63;
    const int wid  = logical * WPB + (threadIdx.x >> 6);
    const int bl   = wid >> 1;
    const int hg   = (wid & 1) * 4;
    const int l    = bl & (L - 1);
    const int b    = bl >> 11;
    const int r    = lane >> 4;
    const int g    = lane & 15;
    const int h    = hg + r;

    int  cols[MAXC];
    bool val[MAXC];
    build_cols(l, cols, val);

    const int qidx   = (bl * H + h) * (E / 4) + g;
    const int kvlane = (b * S * H + h) * 16 + g;
    constexpr int CSTRIDE = H * 16;                 // 128 uint4 per column

    const float4 q = Q4[qidx];

    // One dwordx4 per column: {K 4xbf16 | V 4xbf16}. K half consumed
    // immediately (short live range); V half kept packed (2 VGPR/col).
    float p[MAXC];
    uint2 vv[MAXC];
#pragma unroll
    for (int i = 0; i < MAXC; ++i) {
        const uint4 kv = P[kvlane + cols[i] * CSTRIDE];
        vv[i] = make_uint2(kv.z, kv.w);
        p[i] = fmaf(q.x, bflo(kv.x),
               fmaf(q.y, bfhi(kv.x),
               fmaf(q.z, bflo(kv.y), q.w * bfhi(kv.y))));
    }

    // 16-lane-row sum: 4 pure-DPP stages.
#pragma unroll
    for (int i = 0; i < MAXC; ++i) p[i] = dpp_add<0xB1>(p[i]);
#pragma unroll
    for (int i = 0; i < MAXC; ++i) p[i] = dpp_add<0x4E>(p[i]);
#pragma unroll
    for (int i = 0; i < MAXC; ++i) p[i] = dpp_add<0x141>(p[i]);
#pragma unroll
    for (int i = 0; i < MAXC; ++i) p[i] = dpp_add<0x140>(p[i]);

    const float scale = 0.125f;
#pragma unroll
    for (int i = 0; i < MAXC; ++i)
        p[i] = val[i] ? p[i] * scale : -1e30f;

    float mx[MAXC];
#pragma unroll
    for (int i = 0; i < MAXC; ++i) mx[i] = p[i];
#pragma unroll
    for (int s = 1; s < MAXC; s <<= 1)
#pragma unroll
        for (int i = 0; i + s < MAXC; i += 2 * s)
            mx[i] = fmaxf(mx[i], mx[i + s]);
    const float m = mx[0];

#pragma unroll
    for (int i = 0; i < MAXC; ++i)
        p[i] = __expf(p[i] - m);

    float sm[MAXC];
#pragma unroll
    for (int i = 0; i < MAXC; ++i) sm[i] = p[i];
#pragma unroll
    for (int s = 1; s < MAXC; s <<= 1)
#pragma unroll
        for (int i = 0; i + s < MAXC; i += 2 * s)
            sm[i] += sm[i + s];
    const float inv = 1.0f / sm[0];

    float4 acc = make_float4(0.f, 0.f, 0.f, 0.f);
#pragma unroll
    for (int i = 0; i < MAXC; ++i) {
        acc.x = fmaf(p[i], bflo(vv[i].x), acc.x);
        acc.y = fmaf(p[i], bfhi(vv[i].x), acc.y);
        acc.z = fmaf(p[i], bflo(vv[i].y), acc.z);
        acc.w = fmaf(p[i], bfhi(vv[i].y), acc.w);
    }

    O4[qidx] = make_float4(acc.x * inv, acc.y * inv, acc.z * inv, acc.w * inv);
}

// ---------------- fallback: R4 fp32 kernel (if ws too small) ----------------
__global__ __launch_bounds__(WPB * 64)
void logsparse_attn_f32(const float4* __restrict__ Q4,
                        const float4* __restrict__ K4,
                        const float4* __restrict__ V4,
                        float4* __restrict__ O4) {
    const int logical = (blockIdx.x & 7) * (NBLK / 8) + (blockIdx.x >> 3);
    const int lane = threadIdx.x & 63;
    const int wid  = logical * WPB + (threadIdx.x >> 6);
    const int bl   = wid >> 1;
    const int hg   = (wid & 1) * 4;
    const int l    = bl & (L - 1);
    const int b    = bl >> 11;
    const int r    = lane >> 4;
    const int g    = lane & 15;
    const int h    = hg + r;

    int  cols[MAXC];
    bool val[MAXC];
    build_cols(l, cols, val);

    const int qidx   = (bl * H + h) * (E / 4) + g;
    const int kvlane = (b * S * H + h) * (E / 4) + g;
    constexpr int CSTRIDE4 = H * (E / 4);

    const float4 q = Q4[qidx];

    float p[MAXC];
#pragma unroll
    for (int i = 0; i < MAXC; ++i) {
        const float4 k = K4[kvlane + cols[i] * CSTRIDE4];
        p[i] = fmaf(q.x, k.x, fmaf(q.y, k.y, fmaf(q.z, k.z, q.w * k.w)));
    }
#pragma unroll
    for (int i = 0; i < MAXC; ++i) p[i] = dpp_add<0xB1>(p[i]);
#pragma unroll
    for (int i = 0; i < MAXC; ++i) p[i] = dpp_add<0x4E>(p[i]);
#pragma unroll
    for (int i = 0; i < MAXC; ++i) p[i] = dpp_add<0x141>(p[i]);
#pragma unroll
    for (int i = 0; i < MAXC; ++i) p[i] = dpp_add<0x140>(p[i]);

    const float scale = 0.125f;
    float m = -1e30f;
#pragma unroll
    for (int i = 0; i < MAXC; ++i) {
        p[i] = val[i] ? p[i] * scale : -1e30f;
        m = fmaxf(m, p[i]);
    }
    float sum = 0.f;
#pragma unroll
    for (int i = 0; i < MAXC; ++i) {
        p[i] = __expf(p[i] - m);
        sum += p[i];
    }
    const float inv = 1.0f / sum;

    float4 acc = make_float4(0.f, 0.f, 0.f, 0.f);
#pragma unroll
    for (int i = 0; i < MAXC; ++i) {
        const float4 v = V4[kvlane + cols[i] * CSTRIDE4];
        acc.x = fmaf(p[i], v.x, acc.x);
        acc.y = fmaf(p[i], v.y, acc.y);
        acc.z = fmaf(p[i], v.z, acc.z);
        acc.w = fmaf(p[i], v.w, acc.w);
    }
    O4[qidx] = make_float4(acc.x * inv, acc.y * inv, acc.z * inv, acc.w * inv);
}

extern "C" void kernel_launch(void* const* d_in, const int* in_sizes, int n_in,
                              void* d_out, int out_size, void* d_ws, size_t ws_size,
                              hipStream_t stream) {
    const float4* Q = (const float4*)d_in[0];
    const float4* K = (const float4*)d_in[1];
    const float4* V = (const float4*)d_in[2];
    float4*       O = (float4*)d_out;

    if (ws_size >= PACK_BYTES) {
        uint4* P = (uint4*)d_ws;
        const int pthreads = B * S * H * 16;        // 524288
        pack_kv<<<dim3(pthreads / 256), dim3(256), 0, stream>>>(K, V, P);
        logsparse_attn_bf<<<dim3(NBLK), dim3(WPB * 64), 0, stream>>>(Q, P, O);
    } else {
        logsparse_attn_f32<<<dim3(NBLK), dim3(WPB * 64), 0, stream>>>(Q, K, V, O);
    }
}

// Round 6
// 85.242 us; speedup vs baseline: 1.0691x; 1.0691x over previous
//
#include <hip/hip_runtime.h>

// LogSparseAttention: B=2, L=S=2048, H=8, E=D=64, fp32.
// Mask (win_len=sub_len=2048, log_l=11):
//   l < 22  : causal prefix 0..l
//   l >= 22 : {l-10..l} U {l-10-2^j >= 0, j=0..10}  (<= 22 columns)
//
// R3: 4 rows/wave (4 heads of same (b,l)), 16 lanes/row, pure-DPP reduce.
// R4: XCD-aware block swizzle (contiguous l-slab per XCD).
// R5 (reverted): bf16 packing prepass — bytes were not the wall.
// R6: memory-level parallelism. R2's VGPR_Count=48 shows the compiler was
//     batching the 22 loads through ~6 registers -> ~8-10 serialized
//     round-trips/wave (Little's law: only ~2-3 KB outstanding per CU,
//     matching the observed ~8.6 TB/s logical). Fix: __launch_bounds__(256,2)
//     (256-VGPR cap), load all 22 K cols into registers, issue all 22 V
//     loads BEFORE the reduce/softmax block so the V round-trip overlaps
//     ~600 cyc of VALU work. ~22 KB outstanding per wave.

constexpr int B = 2, L = 2048, S = 2048, H = 8, E = 64;
constexpr int LOGL = 11;
constexpr int MAXC = 2 * LOGL;           // 22
constexpr int ROWS = B * L * H;          // 32768
constexpr int WPB  = 4;                  // waves per block
constexpr int WAVES = ROWS / 4;          // 8192 (4 rows per wave)
constexpr int NBLK  = WAVES / WPB;       // 2048

template<int CTRL>
__device__ __forceinline__ float dpp_add(float x) {
    int y = __builtin_amdgcn_update_dpp(0, __float_as_int(x), CTRL, 0xF, 0xF, true);
    return x + __int_as_float(y);
}

__global__ __launch_bounds__(WPB * 64, 2)   // allow up to 256 VGPRs: MLP > TLP here
void logsparse_attn(const float4* __restrict__ Q4,
                    const float4* __restrict__ K4,
                    const float4* __restrict__ V4,
                    float4* __restrict__ O4) {
    // XCD-aware swizzle: phys block i runs on XCD i%8 -> contiguous l-slab.
    const int logical = (blockIdx.x & 7) * (NBLK / 8) + (blockIdx.x >> 3);

    const int lane = threadIdx.x & 63;
    const int wid  = logical * WPB + (threadIdx.x >> 6);
    const int bl   = wid >> 1;              // b*L + l  (2 waves per (b,l))
    const int hg   = (wid & 1) * 4;         // head group: 0 or 4
    const int l    = bl & (L - 1);
    const int b    = bl >> 11;              // L = 2048
    const int r    = lane >> 4;             // head within wave: 0..3
    const int g    = lane & 15;             // float4 slot within row: 0..15
    const int h    = hg + r;

    // Active-column list — identical for all 4 rows (depends only on l).
    int  cols[MAXC];
    bool val[MAXC];
    if (l < 2 * LOGL) {                     // full causal prefix
#pragma unroll
        for (int i = 0; i < MAXC; ++i) {
            val[i]  = (i <= l);
            cols[i] = val[i] ? i : 0;
        }
    } else {
#pragma unroll
        for (int j = 0; j < LOGL; ++j) {    // l-10 .. l
            cols[j] = l - (LOGL - 1) + j;
            val[j]  = true;
        }
#pragma unroll
        for (int j = 0; j < LOGL; ++j) {    // l-10-2^j
            int c = l - (LOGL - 1) - (1 << j);
            val[LOGL + j]  = (c >= 0);
            cols[LOGL + j] = (c >= 0) ? c : 0;
        }
    }
#pragma unroll
    for (int i = 0; i < MAXC; ++i)
        cols[i] = __builtin_amdgcn_readfirstlane(cols[i]);   // wave-uniform -> SGPR

    const int qidx   = (bl * H + h) * (E / 4) + g;
    const int kvlane = (b * S * H + h) * (E / 4) + g;
    constexpr int CSTRIDE4 = H * (E / 4);   // 128 float4 per column

    const float4 q = Q4[qidx];

    // ---- Phase 1: ALL 22 K loads in flight at once (88 VGPR buffer). ----
    float4 kb[MAXC];
#pragma unroll
    for (int i = 0; i < MAXC; ++i)
        kb[i] = K4[kvlane + cols[i] * CSTRIDE4];

    float p[MAXC];
#pragma unroll
    for (int i = 0; i < MAXC; ++i)
        p[i] = fmaf(q.x, kb[i].x, fmaf(q.y, kb[i].y,
               fmaf(q.z, kb[i].z, q.w * kb[i].w)));

    // ---- Phase 2: issue ALL 22 V loads NOW (kb regs are dead; reuse). ----
    // Independent of the reduce/softmax below -> round-trip overlaps VALU.
    float4 vb[MAXC];
#pragma unroll
    for (int i = 0; i < MAXC; ++i)
        vb[i] = V4[kvlane + cols[i] * CSTRIDE4];

    // 16-lane-row sum: 4 pure-DPP stages (no LDS pipe).
#pragma unroll
    for (int i = 0; i < MAXC; ++i) p[i] = dpp_add<0xB1>(p[i]);   // xor 1
#pragma unroll
    for (int i = 0; i < MAXC; ++i) p[i] = dpp_add<0x4E>(p[i]);   // xor 2
#pragma unroll
    for (int i = 0; i < MAXC; ++i) p[i] = dpp_add<0x141>(p[i]);  // half-mirror
#pragma unroll
    for (int i = 0; i < MAXC; ++i) p[i] = dpp_add<0x140>(p[i]);  // mirror

    // Softmax; masked -> -1e30 -> exp underflows to 0 (matches -1e9*scale).
    const float scale = 0.125f;
#pragma unroll
    for (int i = 0; i < MAXC; ++i)
        p[i] = val[i] ? p[i] * scale : -1e30f;

    float mx[MAXC];
#pragma unroll
    for (int i = 0; i < MAXC; ++i) mx[i] = p[i];
#pragma unroll
    for (int s = 1; s < MAXC; s <<= 1)
#pragma unroll
        for (int i = 0; i + s < MAXC; i += 2 * s)
            mx[i] = fmaxf(mx[i], mx[i + s]);
    const float m = mx[0];

#pragma unroll
    for (int i = 0; i < MAXC; ++i)
        p[i] = __expf(p[i] - m);

    float sm[MAXC];
#pragma unroll
    for (int i = 0; i < MAXC; ++i) sm[i] = p[i];
#pragma unroll
    for (int s = 1; s < MAXC; s <<= 1)
#pragma unroll
        for (int i = 0; i + s < MAXC; i += 2 * s)
            sm[i] += sm[i + s];
    const float inv = 1.0f / sm[0];

    // ---- Phase 3: consume V. ----
    float4 acc = make_float4(0.f, 0.f, 0.f, 0.f);
#pragma unroll
    for (int i = 0; i < MAXC; ++i) {
        acc.x = fmaf(p[i], vb[i].x, acc.x);
        acc.y = fmaf(p[i], vb[i].y, acc.y);
        acc.z = fmaf(p[i], vb[i].z, acc.z);
        acc.w = fmaf(p[i], vb[i].w, acc.w);
    }

    O4[qidx] = make_float4(acc.x * inv, acc.y * inv, acc.z * inv, acc.w * inv);
}

extern "C" void kernel_launch(void* const* d_in, const int* in_sizes, int n_in,
                              void* d_out, int out_size, void* d_ws, size_t ws_size,
                              hipStream_t stream) {
    const float4* Q = (const float4*)d_in[0];
    const float4* K = (const float4*)d_in[1];
    const float4* V = (const float4*)d_in[2];
    float4*       O = (float4*)d_out;

    logsparse_attn<<<dim3(NBLK), dim3(WPB * 64), 0, stream>>>(Q, K, V, O);
}

// Round 7
// 84.808 us; speedup vs baseline: 1.0746x; 1.0051x over previous
//
#include <hip/hip_runtime.h>

// LogSparseAttention: B=2, L=S=2048, H=8, E=D=64, fp32.
// Mask (win_len=sub_len=2048, log_l=11):
//   l < 22  : causal prefix 0..l
//   l >= 22 : {l-10..l} U {l-10-2^j >= 0, j=0..10}  (<= 22 columns)
//
// R3: 4 rows/wave (4 heads), 16 lanes/row, pure-DPP reduce, SGPR cols.
// R4: XCD-aware swizzle (contiguous l-slab per XCD).
// R5 (reverted): bf16 packing — bytes not the wall.
// R6 (reverted): register mega-buffers / 256-VGPR — MLP not the wall.
// R7: intra-CU L1 locality. Adjacent-l rows share 10/11 window columns but
//     previously ran on different CUs (no L1 reuse; every request paid the
//     L2/L3 round trip). Block = 8 waves (512 thr) = 4 consecutive l x both
//     head groups -> co-resident on one CU, window K+V (~56 KB/tile) served
//     largely from L1. Body is the lean R4 one (~50 VGPR, 8 waves/SIMD).

constexpr int B = 2, L = 2048, S = 2048, H = 8, E = 64;
constexpr int LOGL = 11;
constexpr int MAXC = 2 * LOGL;           // 22
constexpr int LT   = 4;                  // l-tile per block
constexpr int WPB  = 8;                  // waves per block (4 l x 2 head-grp)
constexpr int NBLK = B * L / LT;         // 1024

template<int CTRL>
__device__ __forceinline__ float dpp_add(float x) {
    int y = __builtin_amdgcn_update_dpp(0, __float_as_int(x), CTRL, 0xF, 0xF, true);
    return x + __int_as_float(y);
}

__global__ __launch_bounds__(WPB * 64)
void logsparse_attn(const float4* __restrict__ Q4,
                    const float4* __restrict__ K4,
                    const float4* __restrict__ V4,
                    float4* __restrict__ O4) {
    // XCD-aware swizzle: phys block i runs on XCD i%8; XCD x gets the
    // contiguous logical range [x*NBLK/8, (x+1)*NBLK/8)  (512-l slab).
    const int logical = (blockIdx.x & 7) * (NBLK / 8) + (blockIdx.x >> 3);

    const int lane = threadIdx.x & 63;
    const int w    = threadIdx.x >> 6;      // wave in block: 0..7
    const int dl   = w >> 1;                // l offset within tile: 0..3
    const int hg   = (w & 1) * 4;           // head group: 0 or 4
    const int bl   = logical * LT + dl;     // b*L + l
    const int l    = bl & (L - 1);
    const int b    = bl >> 11;              // L = 2048
    const int r    = lane >> 4;             // head within wave: 0..3
    const int g    = lane & 15;             // float4 slot within row: 0..15
    const int h    = hg + r;

    // Active-column list — identical for the 4 heads (depends only on l).
    int  cols[MAXC];
    bool val[MAXC];
    if (l < 2 * LOGL) {                     // full causal prefix
#pragma unroll
        for (int i = 0; i < MAXC; ++i) {
            val[i]  = (i <= l);
            cols[i] = val[i] ? i : 0;
        }
    } else {
#pragma unroll
        for (int j = 0; j < LOGL; ++j) {    // l-10 .. l
            cols[j] = l - (LOGL - 1) + j;
            val[j]  = true;
        }
#pragma unroll
        for (int j = 0; j < LOGL; ++j) {    // l-10-2^j
            int c = l - (LOGL - 1) - (1 << j);
            val[LOGL + j]  = (c >= 0);
            cols[LOGL + j] = (c >= 0) ? c : 0;
        }
    }
#pragma unroll
    for (int i = 0; i < MAXC; ++i)
        cols[i] = __builtin_amdgcn_readfirstlane(cols[i]);   // wave-uniform -> SGPR

    const int qidx   = (bl * H + h) * (E / 4) + g;
    const int kvlane = (b * S * H + h) * (E / 4) + g;
    constexpr int CSTRIDE4 = H * (E / 4);   // 128 float4 per column

    const float4 q = Q4[qidx];

    // Partial dot products: 22 coalesced dwordx4 loads (1 KB/wave/instr).
    float p[MAXC];
#pragma unroll
    for (int i = 0; i < MAXC; ++i) {
        const float4 k = K4[kvlane + cols[i] * CSTRIDE4];
        p[i] = fmaf(q.x, k.x, fmaf(q.y, k.y, fmaf(q.z, k.z, q.w * k.w)));
    }

    // 16-lane-row sum: 4 pure-DPP stages (no LDS pipe).
#pragma unroll
    for (int i = 0; i < MAXC; ++i) p[i] = dpp_add<0xB1>(p[i]);   // xor 1
#pragma unroll
    for (int i = 0; i < MAXC; ++i) p[i] = dpp_add<0x4E>(p[i]);   // xor 2
#pragma unroll
    for (int i = 0; i < MAXC; ++i) p[i] = dpp_add<0x141>(p[i]);  // half-mirror
#pragma unroll
    for (int i = 0; i < MAXC; ++i) p[i] = dpp_add<0x140>(p[i]);  // mirror

    // Softmax; masked -> -1e30 -> exp underflows to 0 (matches -1e9*scale).
    const float scale = 0.125f;
#pragma unroll
    for (int i = 0; i < MAXC; ++i)
        p[i] = val[i] ? p[i] * scale : -1e30f;

    float mx[MAXC];
#pragma unroll
    for (int i = 0; i < MAXC; ++i) mx[i] = p[i];
#pragma unroll
    for (int s = 1; s < MAXC; s <<= 1)
#pragma unroll
        for (int i = 0; i + s < MAXC; i += 2 * s)
            mx[i] = fmaxf(mx[i], mx[i + s]);
    const float m = mx[0];

#pragma unroll
    for (int i = 0; i < MAXC; ++i)
        p[i] = __expf(p[i] - m);

    float sm[MAXC];
#pragma unroll
    for (int i = 0; i < MAXC; ++i) sm[i] = p[i];
#pragma unroll
    for (int s = 1; s < MAXC; s <<= 1)
#pragma unroll
        for (int i = 0; i + s < MAXC; i += 2 * s)
            sm[i] += sm[i + s];
    const float inv = 1.0f / sm[0];

    // O = sum_i w_i * V[col_i]
    float4 acc = make_float4(0.f, 0.f, 0.f, 0.f);
#pragma unroll
    for (int i = 0; i < MAXC; ++i) {
        const float4 v = V4[kvlane + cols[i] * CSTRIDE4];
        acc.x = fmaf(p[i], v.x, acc.x);
        acc.y = fmaf(p[i], v.y, acc.y);
        acc.z = fmaf(p[i], v.z, acc.z);
        acc.w = fmaf(p[i], v.w, acc.w);
    }

    O4[qidx] = make_float4(acc.x * inv, acc.y * inv, acc.z * inv, acc.w * inv);
}

extern "C" void kernel_launch(void* const* d_in, const int* in_sizes, int n_in,
                              void* d_out, int out_size, void* d_ws, size_t ws_size,
                              hipStream_t stream) {
    const float4* Q = (const float4*)d_in[0];
    const float4* K = (const float4*)d_in[1];
    const float4* V = (const float4*)d_in[2];
    float4*       O = (float4*)d_out;

    logsparse_attn<<<dim3(NBLK), dim3(WPB * 64), 0, stream>>>(Q, K, V, O);
}